// Round 6
// baseline (220.315 us; speedup 1.0000x reference)
//
#include <hip/hip_runtime.h>
#include <hip/hip_bf16.h>
#include <math.h>

// CodecAttention: x->QKV proj (bf16 MFMA, V written transposed) -> RMSNorm(q,k)
// -> MFMA sliding-window ALiBi attention (win=16) -> out proj.
// B=4 T=2048 DIM=1024 H=8 D=128.

#define TSEQ 2048
#define DIMW 1024
#define NHEAD 8
#define WIN 16

typedef __bf16 bf16x8_t __attribute__((ext_vector_type(8)));
typedef float f32x4_t __attribute__((ext_vector_type(4)));

__device__ __forceinline__ unsigned short f2bf(float f) {
  unsigned u = __float_as_uint(f);
  u += 0x7fffu + ((u >> 16) & 1u);   // round-to-nearest-even
  return (unsigned short)(u >> 16);
}
__device__ __forceinline__ float bflo(unsigned u) { return __uint_as_float(u << 16); }
__device__ __forceinline__ float bfhi(unsigned u) { return __uint_as_float(u & 0xffff0000u); }

// ---------- f32 -> bf16 conversion of x ----------
__global__ __launch_bounds__(256)
void k_conv_x(const float* __restrict__ x, unsigned short* __restrict__ xb, int n4) {
  int i = blockIdx.x * 256 + threadIdx.x;
  if (i >= n4) return;
  float4 v = ((const float4*)x)[i];
  ushort4 o;
  o.x = f2bf(v.x); o.y = f2bf(v.y); o.z = f2bf(v.z); o.w = f2bf(v.w);
  ((ushort4*)xb)[i] = o;
}

// ---------- transpose + convert weights: Wt[z][n][k] = w_z[k][n] ----------
__global__ __launch_bounds__(256)
void k_conv_w(const float* __restrict__ wq, const float* __restrict__ wk,
              const float* __restrict__ wv, const float* __restrict__ wo,
              unsigned short* __restrict__ Wt) {
  __shared__ float tile[32][33];
  const int z = blockIdx.z;
  const float* src = (z == 0) ? wq : (z == 1) ? wk : (z == 2) ? wv : wo;
  const int n0 = blockIdx.x * 32;
  const int k0 = blockIdx.y * 32;
  const int tx = threadIdx.x, ty = threadIdx.y;  // 32 x 8
#pragma unroll
  for (int i = 0; i < 4; ++i)
    tile[ty + 8 * i][tx] = src[(size_t)(k0 + ty + 8 * i) * DIMW + n0 + tx];
  __syncthreads();
#pragma unroll
  for (int i = 0; i < 4; ++i)
    Wt[(size_t)z * DIMW * DIMW + (size_t)(n0 + ty + 8 * i) * DIMW + k0 + tx] =
        f2bf(tile[tx][ty + 8 * i]);
}

// ---------- bf16 TN GEMM, depth-3 slice-ring pipeline ----------
// Block tile 256(M) x BN, 512 threads = 8 waves (2 rows x 4 cols), wave tile
// 128 x BN/4.  K consumed in 32-wide SLICES; 4-slot LDS ring (slot = slice&3,
// slot size = A 16KB + B BN*64B).  Prefetch distance 3 slices (T3/T4):
//   per slice s: vmcnt(2*LPT) retires exactly slice s's LPT loads (s+1,s+2
//   stay in flight -- never drains to 0 until the tail); s_barrier makes the
//   landing collective; issue slice s+3 into slot (s-1)&3 -- every wave's
//   ds_reads of slice s-1 were forced complete (compiler lgkmcnt before the
//   MFMAs consuming them) BEFORE that wave reached the PREVIOUS barrier, so
//   no write-while-read window.  One barrier per slice.  Loads are issued
//   ~3 slices (>1200 cy) before their vmcnt -- covers L2/LLC/HBM latency
//   (R5's 2-phase-deep version stalled every half-tile; this is the fix).
// Staging: global_load_lds width 16, source col-group pre-swizzled with the
// involution kg = g ^ ((row>>1)&3) (R4/R5-verified: SQ_LDS_BANK_CONFLICT==0);
// fragment ds_read_b128 applies the same involution.
// MODE 0: bf16 out; col<2048 -> Cb[row][2048]; col>=2048 (V third) written
//         TRANSPOSED into Vt[(b*8+h)*128+d][t].  MODE 1: f32 out Cf[row][N].
#define GLDS(gp, lp)                                                        \
  __builtin_amdgcn_global_load_lds(                                         \
      (const __attribute__((address_space(1))) void*)(gp),                  \
      (__attribute__((address_space(3))) void*)(lp), 16, 0, 0)

template <int MODE, int BN>
__global__ __launch_bounds__(512, 2)
void k_gemm(const unsigned short* __restrict__ A,   // [M][K] bf16
            const unsigned short* __restrict__ Bt,  // [N][K] bf16
            unsigned short* __restrict__ Cb,        // bf16 out (MODE 0, q|k part)
            unsigned short* __restrict__ Vt,        // bf16 out (MODE 0, v part, transposed)
            float* __restrict__ Cf,                 // f32 out  (MODE 1)
            int M, int N, int K) {
  constexpr int WN = BN / 4;          // wave n-width
  constexpr int NF = WN / 16;         // n-frags per wave (4 or 2)
  constexpr int ASL = 16384;          // A slice bytes (256 rows x 64B)
  constexpr int BSL = BN * 64;        // B slice bytes
  constexpr int SLICE = ASL + BSL;    // 32KB (BN=256) / 24KB (BN=128)
  __shared__ __align__(16) unsigned char smem[4 * SLICE];
  const int tid = threadIdx.x;
  const int lane = tid & 63;
  const int w = tid >> 6;             // wave 0..7
  const int wm = w >> 2, wn = w & 3;  // 2 x 4

  // XCD-aware bijective swizzle (grids are multiples of 8).  Side effect of
  // this mapping: all 12 bx-blocks sharing one A row-panel land on the same
  // XCD -> A panel stays L2-resident.
  const int nwg = gridDim.x * gridDim.y;
  int flat = blockIdx.y * gridDim.x + blockIdx.x;
  flat = (flat & 7) * (nwg >> 3) + (flat >> 3);
  const int bx = flat % gridDim.x;
  const int by = flat / gridDim.x;

  // staging addressing: issue h covers LDS rows h*128..+127 (row = 64B);
  // thread (w,lane): row = h*128 + w*16 + (lane>>2); source col-group
  // pre-swizzled: cg = (lane&3) ^ ((lane>>3)&3)  (row bits 1..2 = lane>>3).
  const int r2 = lane >> 2;
  const int cg = ((lane & 3) ^ ((lane >> 3) & 3)) * 8;  // elements

#define IA(sl_, ks_, h_)                                                         \
  GLDS(A + (size_t)(by * 256 + (h_)*128 + w * 16 + r2) * K + (ks_)*32 + cg,      \
       smem + (sl_)*SLICE + ((h_)*128 + w * 16) * 64)
#define IB(sl_, ks_, h_)                                                         \
  GLDS(Bt + (size_t)(bx * BN + (h_)*128 + w * 16 + r2) * K + (ks_)*32 + cg,      \
       smem + (sl_)*SLICE + ASL + ((h_)*128 + w * 16) * 64)
#define STAGE(ks_)                                                               \
  do {                                                                           \
    const int sl_ = (ks_) & 3;                                                   \
    IA(sl_, (ks_), 0); IA(sl_, (ks_), 1);                                        \
    IB(sl_, (ks_), 0);                                                           \
    if (BN == 256) IB(sl_, (ks_), 1);                                            \
  } while (0)

  // fragment reads: row = wm*128 + m*16 + (lane&15); kg = lane>>4;
  // slot g = kg ^ ((row>>1)&3) = (lane>>4) ^ ((lane>>1)&3).
  const int swz = ((lane >> 4) ^ ((lane >> 1) & 3)) * 16;
  const int aBase = (wm * 128 + (lane & 15)) * 64 + swz;
  const int bBase = ASL + (wn * WN + (lane & 15)) * 64 + swz;

  f32x4_t acc[8][NF];
#pragma unroll
  for (int m = 0; m < 8; ++m)
#pragma unroll
    for (int n = 0; n < NF; ++n) acc[m][n] = (f32x4_t){0.f, 0.f, 0.f, 0.f};

  const int NS = K >> 5;  // 32 slices
  STAGE(0); STAGE(1); STAGE(2);   // 3 slices in flight
#pragma unroll 1
  for (int s = 0; s < NS; ++s) {
    if (s + 2 < NS) {
      if (BN == 256) asm volatile("s_waitcnt vmcnt(8)" ::: "memory");
      else           asm volatile("s_waitcnt vmcnt(6)" ::: "memory");
    } else if (s + 1 < NS) {
      if (BN == 256) asm volatile("s_waitcnt vmcnt(4)" ::: "memory");
      else           asm volatile("s_waitcnt vmcnt(3)" ::: "memory");
    } else {
      asm volatile("s_waitcnt vmcnt(0)" ::: "memory");
    }
    asm volatile("s_barrier" ::: "memory");
    if (s + 3 < NS) STAGE(s + 3);
    const unsigned char* sp = smem + (s & 3) * SLICE;
    bf16x8_t af[4], bfr[NF];
#pragma unroll
    for (int n = 0; n < NF; ++n) bfr[n] = *(const bf16x8_t*)(sp + bBase + n * 1024);
#pragma unroll
    for (int m = 0; m < 4; ++m) af[m] = *(const bf16x8_t*)(sp + aBase + m * 1024);
    __builtin_amdgcn_s_setprio(1);
#pragma unroll
    for (int m = 0; m < 4; ++m)
#pragma unroll
      for (int n = 0; n < NF; ++n)
        acc[m][n] = __builtin_amdgcn_mfma_f32_16x16x32_bf16(af[m], bfr[n], acc[m][n], 0, 0, 0);
    __builtin_amdgcn_s_setprio(0);
#pragma unroll
    for (int m = 0; m < 4; ++m) af[m] = *(const bf16x8_t*)(sp + aBase + (4 + m) * 1024);
    __builtin_amdgcn_s_setprio(1);
#pragma unroll
    for (int m = 0; m < 4; ++m)
#pragma unroll
      for (int n = 0; n < NF; ++n)
        acc[4 + m][n] =
            __builtin_amdgcn_mfma_f32_16x16x32_bf16(af[m], bfr[n], acc[4 + m][n], 0, 0, 0);
    __builtin_amdgcn_s_setprio(0);
  }

  // C/D layout (m89-verified): col = lane&15, row = (lane>>4)*4 + reg
  const int row0 = by * 256 + wm * 128 + ((lane >> 4) << 2);
  const int col0 = bx * BN + wn * WN + (lane & 15);
  if (MODE == 1) {
#pragma unroll
    for (int m = 0; m < 8; ++m)
#pragma unroll
      for (int n = 0; n < NF; ++n)
#pragma unroll
        for (int r = 0; r < 4; ++r)
          Cf[(size_t)(row0 + m * 16 + r) * N + col0 + n * 16] = acc[m][n][r];
  } else if (bx * BN < 2048) {
#pragma unroll
    for (int m = 0; m < 8; ++m)
#pragma unroll
      for (int n = 0; n < NF; ++n)
#pragma unroll
        for (int r = 0; r < 4; ++r)
          Cb[(size_t)(row0 + m * 16 + r) * 2048 + col0 + n * 16] = f2bf(acc[m][n][r]);
  } else {
#pragma unroll
    for (int m = 0; m < 8; ++m)
#pragma unroll
      for (int n = 0; n < NF; ++n)
#pragma unroll
        for (int r = 0; r < 4; ++r) {
          const int row = row0 + m * 16 + r;
          const int vcol = col0 + n * 16 - 2048;
          const int hh = vcol >> 7, dd = vcol & 127;
          const int bb = row >> 11, tt = row & 2047;
          Vt[((size_t)(bb * NHEAD + hh) * 128 + dd) * TSEQ + tt] = f2bf(acc[m][n][r]);
        }
  }
#undef IA
#undef IB
#undef STAGE
}

// ---------- in-place RMSNorm on q (cols 0..1023) and k (cols 1024..2047) ----------
__global__ __launch_bounds__(256)
void k_rmsnorm(unsigned short* __restrict__ qk, const float* __restrict__ qw,
               const float* __restrict__ kw) {
  const int row = blockIdx.x;
  const int tid = threadIdx.x;
  unsigned short* base = qk + (size_t)row * 2048;
  uint2 uq = *(const uint2*)(base + tid * 4);
  uint2 uk = *(const uint2*)(base + 1024 + tid * 4);
  float q0 = bflo(uq.x), q1 = bfhi(uq.x), q2 = bflo(uq.y), q3 = bfhi(uq.y);
  float k0 = bflo(uk.x), k1 = bfhi(uk.x), k2 = bflo(uk.y), k3 = bfhi(uk.y);
  float sq = q0 * q0 + q1 * q1 + q2 * q2 + q3 * q3;
  float sk = k0 * k0 + k1 * k1 + k2 * k2 + k3 * k3;
#pragma unroll
  for (int off = 32; off > 0; off >>= 1) {
    sq += __shfl_xor(sq, off);
    sk += __shfl_xor(sk, off);
  }
  __shared__ float red[8];
  const int w = tid >> 6;
  if ((tid & 63) == 0) { red[w] = sq; red[4 + w] = sk; }
  __syncthreads();
  sq = red[0] + red[1] + red[2] + red[3];
  sk = red[4] + red[5] + red[6] + red[7];
  const float rq = rsqrtf(sq * (1.0f / 1024.0f) + 1e-6f);
  const float rk = rsqrtf(sk * (1.0f / 1024.0f) + 1e-6f);
  const int c = tid * 4;
  uint2 oq, ok;
  oq.x = (unsigned)f2bf(q0 * rq * qw[c]) | ((unsigned)f2bf(q1 * rq * qw[c + 1]) << 16);
  oq.y = (unsigned)f2bf(q2 * rq * qw[c + 2]) | ((unsigned)f2bf(q3 * rq * qw[c + 3]) << 16);
  ok.x = (unsigned)f2bf(k0 * rk * kw[c]) | ((unsigned)f2bf(k1 * rk * kw[c + 1]) << 16);
  ok.y = (unsigned)f2bf(k2 * rk * kw[c + 2]) | ((unsigned)f2bf(k3 * rk * kw[c + 3]) << 16);
  *(uint2*)(base + tid * 4) = oq;
  *(uint2*)(base + 1024 + tid * 4) = ok;
}

// ---------- MFMA sliding-window ALiBi attention ----------
// One wave per 16 queries of one (b,h). Key window: 32 keys [t0-16, t0+16).
// Swapped QK^T (A=K, B=Q) -> S^T: lane holds query c=lane&15, keys g*4+r (+16).
// Softmax: in-lane over 8 + shfl_xor(16,32). P -> padded LDS -> A-frag for PV.
// V read from transposed Vt buffer as b128 B-frags.
__global__ __launch_bounds__(256)
void k_attn(const unsigned short* __restrict__ qk,   // [8192][2048] q|k (normalized)
            const unsigned short* __restrict__ vt,   // [(b*8+h)*128+d][2048]
            unsigned short* __restrict__ outb) {     // [8192][1024] bf16
  __shared__ __align__(16) unsigned char plds_all[4][1280];  // 16 rows x 80B (40 elems)
  const int lane = threadIdx.x & 63;
  const int wv = threadIdx.x >> 6;
  unsigned char* plds = plds_all[wv];
  const int bh = blockIdx.y;                 // 0..31
  const int b = bh >> 3, h = bh & 7;
  const int t0 = blockIdx.x * 64 + wv * 16;
  const int g = lane >> 4, c = lane & 15;
  const int jlo = t0 - 16;

  // Q B-fragments: Q[t0+c][kc*32 + g*8 .. +8]
  const unsigned short* qrow = qk + (size_t)(b * TSEQ + t0 + c) * 2048 + h * 128 + g * 8;
  bf16x8_t qf[4];
#pragma unroll
  for (int kc = 0; kc < 4; ++kc) qf[kc] = *(const bf16x8_t*)(qrow + kc * 32);

  // K A-fragments (2 key-tiles); clamp negative rows (masked anyway)
  const int j0 = jlo + c;
  const int j0c = (j0 < 0) ? 0 : j0;
  const unsigned short* krow0 = qk + (size_t)(b * TSEQ + j0c) * 2048 + 1024 + h * 128 + g * 8;
  const unsigned short* krow1 = qk + (size_t)(b * TSEQ + t0 + c) * 2048 + 1024 + h * 128 + g * 8;
  bf16x8_t kf0[4], kf1[4];
#pragma unroll
  for (int kc = 0; kc < 4; ++kc) {
    kf0[kc] = *(const bf16x8_t*)(krow0 + kc * 32);
    kf1[kc] = *(const bf16x8_t*)(krow1 + kc * 32);
  }

  f32x4_t s0 = (f32x4_t){0.f, 0.f, 0.f, 0.f};
  f32x4_t s1 = (f32x4_t){0.f, 0.f, 0.f, 0.f};
#pragma unroll
  for (int kc = 0; kc < 4; ++kc) {
    s0 = __builtin_amdgcn_mfma_f32_16x16x32_bf16(kf0[kc], qf[kc], s0, 0, 0, 0);
    s1 = __builtin_amdgcn_mfma_f32_16x16x32_bf16(kf1[kc], qf[kc], s1, 0, 0, 0);
  }

  // scores + mask + bias. key kk = z*16 + g*4 + r; query = c; rel = kk-16-c.
  const float scale = 0.08838834764831845f;  // 1/sqrt(128)
  const float slope = 1.0f / (float)(1 << h);
  float val[8];
#pragma unroll
  for (int z = 0; z < 2; ++z)
#pragma unroll
    for (int r = 0; r < 4; ++r) {
      const int kk = z * 16 + g * 4 + r;
      const int rel = kk - 16 - c;
      const bool ok = (rel <= 0) & (rel >= -WIN) & (jlo + kk >= 0);
      const float sc = (z == 0) ? s0[r] : s1[r];
      val[z * 4 + r] = ok ? (sc * scale + slope * (float)rel) : -1.0e30f;
    }
  float m = val[0];
#pragma unroll
  for (int i = 1; i < 8; ++i) m = fmaxf(m, val[i]);
  m = fmaxf(m, __shfl_xor(m, 16));
  m = fmaxf(m, __shfl_xor(m, 32));
  float e[8], s = 0.f;
#pragma unroll
  for (int i = 0; i < 8; ++i) { e[i] = __expf(val[i] - m); s += e[i]; }
  s += __shfl_xor(s, 16);
  s += __shfl_xor(s, 32);
  const float inv = 1.0f / s;

  // P -> LDS [query c][key kk], row stride 40 elems (80B): 2-way banks = free
#pragma unroll
  for (int z = 0; z < 2; ++z) {
    uint2 pk;
    pk.x = (unsigned)f2bf(e[z * 4 + 0] * inv) | ((unsigned)f2bf(e[z * 4 + 1] * inv) << 16);
    pk.y = (unsigned)f2bf(e[z * 4 + 2] * inv) | ((unsigned)f2bf(e[z * 4 + 3] * inv) << 16);
    *(uint2*)(plds + c * 80 + z * 32 + g * 8) = pk;
  }
  // A-fragment of P: row=c (query), keys g*8..+8
  const bf16x8_t pf = *(const bf16x8_t*)(plds + c * 80 + g * 16);

  // PV: B-frag = V[jlo + g*8 + i][d0 + c] = Vt[d0+c][jlo + g*8 ...]
  const int vc0 = jlo + g * 8;
  const int vcc = (vc0 < 0) ? 0 : vc0;   // garbage rows get zero weight
  const unsigned short* vbase = vt + (size_t)(bh * 128 + c) * TSEQ + vcc;
  unsigned short* orow = outb + (size_t)(b * TSEQ + t0) * 1024 + h * 128 + c;
#pragma unroll
  for (int n = 0; n < 8; ++n) {
    const bf16x8_t vf = *(const bf16x8_t*)(vbase + (size_t)n * 16 * TSEQ);
    f32x4_t o = __builtin_amdgcn_mfma_f32_16x16x32_bf16(pf, vf, (f32x4_t){0.f, 0.f, 0.f, 0.f},
                                                        0, 0, 0);
    // C: row=(g*4+r)=query, col=c=d within chunk n
#pragma unroll
    for (int r = 0; r < 4; ++r)
      orow[(size_t)(g * 4 + r) * 1024 + n * 16] = f2bf(o[r]);
  }
}

extern "C" void kernel_launch(void* const* d_in, const int* in_sizes, int n_in,
                              void* d_out, int out_size, void* d_ws, size_t ws_size,
                              hipStream_t stream) {
  const float* x = (const float*)d_in[0];
  const float* wq = (const float*)d_in[1];
  const float* wk = (const float*)d_in[2];
  const float* wv = (const float*)d_in[3];
  const float* wo = (const float*)d_in[4];
  const float* qnw = (const float*)d_in[5];
  const float* knw = (const float*)d_in[6];
  float* out = (float*)d_out;

  const int M = 4 * TSEQ;  // 8192 rows
  // workspace (75.5 MB):
  //   xb  [M][1024] bf16 (16.8 MB)  -- x bf16; later reused as attention output
  //   Wt  [4][1024][1024] bf16 (8.4 MB)
  //   qk  [M][2048] bf16 (33.5 MB)  -- q|k (normalized in place)
  //   Vt  [32][128][2048] bf16 (16.8 MB) -- V transposed per (b,h)
  unsigned short* xb = (unsigned short*)d_ws;
  unsigned short* Wt = xb + (size_t)M * DIMW;
  unsigned short* qkb = Wt + (size_t)4 * DIMW * DIMW;
  unsigned short* Vt = qkb + (size_t)M * 2048;
  if (ws_size < ((size_t)M * DIMW + (size_t)4 * DIMW * DIMW + (size_t)M * 2048 +
                 (size_t)M * 2048) * 2) return;

  k_conv_x<<<(M * DIMW / 4 + 255) / 256, 256, 0, stream>>>(x, xb, M * DIMW / 4);
  k_conv_w<<<dim3(32, 32, 4), dim3(32, 8), 0, stream>>>(wq, wk, wv, wo, Wt);
  k_gemm<0, 256><<<dim3(12, 32), 512, 0, stream>>>(xb, Wt, qkb, Vt, nullptr, M, 3072, 1024);
  k_rmsnorm<<<M, 256, 0, stream>>>(qkb, qnw, knw);
  k_attn<<<dim3(TSEQ / 64, 32), 256, 0, stream>>>(qkb, Vt, xb);  // xb = attn out
  k_gemm<1, 128><<<dim3(8, 32), 512, 0, stream>>>(xb, Wt + (size_t)3 * DIMW * DIMW, nullptr,
                                                  nullptr, out, M, 1024, 1024);
}

// Round 7
// 215.525 us; speedup vs baseline: 1.0222x; 1.0222x over previous
//
#include <hip/hip_runtime.h>
#include <hip/hip_bf16.h>
#include <math.h>

// CodecAttention: x->QKV proj (bf16 MFMA, V written tiled-transposed) ->
// RMSNorm(q,k) -> MFMA sliding-window ALiBi attention (win=16) -> out proj.
// B=4 T=2048 DIM=1024 H=8 D=128.

#define TSEQ 2048
#define DIMW 1024
#define NHEAD 8
#define WIN 16

typedef __bf16 bf16x8_t __attribute__((ext_vector_type(8)));
typedef float f32x4_t __attribute__((ext_vector_type(4)));

__device__ __forceinline__ unsigned short f2bf(float f) {
  unsigned u = __float_as_uint(f);
  u += 0x7fffu + ((u >> 16) & 1u);   // round-to-nearest-even
  return (unsigned short)(u >> 16);
}
__device__ __forceinline__ float bflo(unsigned u) { return __uint_as_float(u << 16); }
__device__ __forceinline__ float bfhi(unsigned u) { return __uint_as_float(u & 0xffff0000u); }

// ---------- f32 -> bf16 conversion of x ----------
__global__ __launch_bounds__(256)
void k_conv_x(const float* __restrict__ x, unsigned short* __restrict__ xb, int n4) {
  int i = blockIdx.x * 256 + threadIdx.x;
  if (i >= n4) return;
  float4 v = ((const float4*)x)[i];
  ushort4 o;
  o.x = f2bf(v.x); o.y = f2bf(v.y); o.z = f2bf(v.z); o.w = f2bf(v.w);
  ((ushort4*)xb)[i] = o;
}

// ---------- transpose + convert weights: Wt[z][n][k] = w_z[k][n] ----------
__global__ __launch_bounds__(256)
void k_conv_w(const float* __restrict__ wq, const float* __restrict__ wk,
              const float* __restrict__ wv, const float* __restrict__ wo,
              unsigned short* __restrict__ Wt) {
  __shared__ float tile[32][33];
  const int z = blockIdx.z;
  const float* src = (z == 0) ? wq : (z == 1) ? wk : (z == 2) ? wv : wo;
  const int n0 = blockIdx.x * 32;
  const int k0 = blockIdx.y * 32;
  const int tx = threadIdx.x, ty = threadIdx.y;  // 32 x 8
#pragma unroll
  for (int i = 0; i < 4; ++i)
    tile[ty + 8 * i][tx] = src[(size_t)(k0 + ty + 8 * i) * DIMW + n0 + tx];
  __syncthreads();
#pragma unroll
  for (int i = 0; i < 4; ++i)
    Wt[(size_t)z * DIMW * DIMW + (size_t)(n0 + ty + 8 * i) * DIMW + k0 + tx] =
        f2bf(tile[tx][ty + 8 * i]);
}

// ---------- bf16 TN GEMM: 128x128 tile, ring-3, 3 blocks/CU ----------
// 256 threads = 4 waves (2x2) of 64x64 (acc = 64 regs -> ~124 VGPR total ->
// launch_bounds(256,3) => 12 waves/CU, 3 blocks/CU of cross-block TLP; this
// is the m97 residency regime, which R3-R6's 8-wave/220-VGPR configs lacked).
// K in 32-wide slices; ring-3 (slot = s%3, 16KB each), prefetch distance 2:
//   per slice s: vmcnt(4) retires exactly slice s's 4 loads (s+1's stay in
//   flight -- never 0 until tail); s_barrier (collective landing); STAGE(s+2)
//   into slot (s+2)%3 == (s-1)%3 -- every wave's reads of slice s-1 finished
//   (lgkmcnt before its MFMAs) before that wave reached THIS barrier => no
//   write-while-read. One barrier per slice.
// Staging source col-group pre-swizzled with involution kg = g ^ ((row>>1)&3)
// (R4/R5/R6-verified: SQ_LDS_BANK_CONFLICT == 0); frag reads apply the same.
// MODE 0: bf16 out; col<2048 -> Cb[row][2048]; col>=2048 (V third) written
//         into tiled-transposed Vt2[bh][t>>3][d][t&7] (coalesced attn reads).
// MODE 1: f32 out Cf[row][N].
#define GLDS(gp, lp)                                                        \
  __builtin_amdgcn_global_load_lds(                                         \
      (const __attribute__((address_space(1))) void*)(gp),                  \
      (__attribute__((address_space(3))) void*)(lp), 16, 0, 0)

template <int MODE>
__global__ __launch_bounds__(256, 3)
void k_gemm(const unsigned short* __restrict__ A,   // [M][K] bf16
            const unsigned short* __restrict__ Bt,  // [N][K] bf16
            unsigned short* __restrict__ Cb,        // bf16 out (MODE 0, q|k part)
            unsigned short* __restrict__ Vt,        // bf16 out (MODE 0, v part, tiled)
            float* __restrict__ Cf,                 // f32 out  (MODE 1)
            int M, int N, int K) {
  __shared__ __align__(16) unsigned char smem[49152];  // 3 x (A 8KB + B 8KB)
  const int tid = threadIdx.x;
  const int lane = tid & 63;
  const int w = tid >> 6;             // wave 0..3
  const int wm = w >> 1, wn = w & 1;  // 2 x 2

  // XCD-aware bijective swizzle (grids are multiples of 8)
  const int nwg = gridDim.x * gridDim.y;
  int flat = blockIdx.y * gridDim.x + blockIdx.x;
  flat = (flat & 7) * (nwg >> 3) + (flat >> 3);
  const int bx = flat % gridDim.x;
  const int by = flat / gridDim.x;

  // staging: per slice per thread 2 A + 2 B loads (16B each).
  // issue h covers LDS rows h*64 + w*16 + (lane>>2); source col-group
  // pre-swizzled: cg = (lane&3) ^ ((lane>>3)&3)   (row bits 1..2 = lane>>3).
  const int r2 = lane >> 2;
  const int cg = ((lane & 3) ^ ((lane >> 3) & 3)) * 8;  // elements

#define IA(sl_, ks_, h_)                                                       \
  GLDS(A + (size_t)(by * 128 + (h_)*64 + w * 16 + r2) * K + (ks_)*32 + cg,     \
       smem + (sl_)*16384 + ((h_)*64 + w * 16) * 64)
#define IB(sl_, ks_, h_)                                                       \
  GLDS(Bt + (size_t)(bx * 128 + (h_)*64 + w * 16 + r2) * K + (ks_)*32 + cg,    \
       smem + (sl_)*16384 + 8192 + ((h_)*64 + w * 16) * 64)
#define STAGE(ks_)                                                             \
  do {                                                                         \
    const int sl_ = (ks_) % 3;                                                 \
    IA(sl_, (ks_), 0); IB(sl_, (ks_), 0);                                      \
    IA(sl_, (ks_), 1); IB(sl_, (ks_), 1);                                      \
  } while (0)

  // frag reads: row = wm*64 + m*16 + (lane&15); kg = lane>>4;
  // slot g = kg ^ ((row>>1)&3) = (lane>>4) ^ ((lane>>1)&3).
  const int swz = ((lane >> 4) ^ ((lane >> 1) & 3)) * 16;
  const int aRd = (wm * 64 + (lane & 15)) * 64 + swz;
  const int bRd = 8192 + (wn * 64 + (lane & 15)) * 64 + swz;

  f32x4_t acc[4][4];
#pragma unroll
  for (int m = 0; m < 4; ++m)
#pragma unroll
    for (int n = 0; n < 4; ++n) acc[m][n] = (f32x4_t){0.f, 0.f, 0.f, 0.f};

  const int NS = K >> 5;  // 32 slices
  STAGE(0); STAGE(1);     // distance 2: 8 loads in flight
#pragma unroll 1
  for (int s = 0; s < NS; ++s) {
    if (s + 1 < NS) asm volatile("s_waitcnt vmcnt(4)" ::: "memory");
    else            asm volatile("s_waitcnt vmcnt(0)" ::: "memory");
    asm volatile("s_barrier" ::: "memory");
    if (s + 2 < NS) STAGE(s + 2);
    const unsigned char* sp = smem + (s % 3) * 16384;
    bf16x8_t af[4], bfr[4];
#pragma unroll
    for (int n = 0; n < 4; ++n) bfr[n] = *(const bf16x8_t*)(sp + bRd + n * 1024);
#pragma unroll
    for (int m = 0; m < 4; ++m) af[m] = *(const bf16x8_t*)(sp + aRd + m * 1024);
    __builtin_amdgcn_s_setprio(1);
#pragma unroll
    for (int m = 0; m < 4; ++m)
#pragma unroll
      for (int n = 0; n < 4; ++n)
        acc[m][n] = __builtin_amdgcn_mfma_f32_16x16x32_bf16(af[m], bfr[n], acc[m][n], 0, 0, 0);
    __builtin_amdgcn_s_setprio(0);
  }

  // C/D layout (m89-verified): col = lane&15, row = (lane>>4)*4 + reg
  const int row0 = by * 128 + wm * 64 + ((lane >> 4) << 2);
  const int col0 = bx * 128 + wn * 64 + (lane & 15);
  if (MODE == 1) {
#pragma unroll
    for (int m = 0; m < 4; ++m)
#pragma unroll
      for (int n = 0; n < 4; ++n)
#pragma unroll
        for (int r = 0; r < 4; ++r)
          Cf[(size_t)(row0 + m * 16 + r) * N + col0 + n * 16] = acc[m][n][r];
  } else if (bx * 128 < 2048) {
#pragma unroll
    for (int m = 0; m < 4; ++m)
#pragma unroll
      for (int n = 0; n < 4; ++n)
#pragma unroll
        for (int r = 0; r < 4; ++r)
          Cb[(size_t)(row0 + m * 16 + r) * 2048 + col0 + n * 16] = f2bf(acc[m][n][r]);
  } else {
    // Vt2[bh][t>>3][d][t&7]; row0 % 4 == 0 so 4-r runs never cross a t-chunk
#pragma unroll
    for (int m = 0; m < 4; ++m)
#pragma unroll
      for (int n = 0; n < 4; ++n)
#pragma unroll
        for (int r = 0; r < 4; ++r) {
          const int row = row0 + m * 16 + r;
          const int vcol = col0 + n * 16 - 2048;
          const int hh = vcol >> 7, dd = vcol & 127;
          const int bb = row >> 11, tt = row & 2047;
          Vt[((((size_t)(bb * NHEAD + hh)) * 256 + (tt >> 3)) * 128 + dd) * 8 + (tt & 7)] =
              f2bf(acc[m][n][r]);
        }
  }
#undef IA
#undef IB
#undef STAGE
}

// ---------- in-place RMSNorm on q (cols 0..1023) and k (cols 1024..2047) ----------
__global__ __launch_bounds__(256)
void k_rmsnorm(unsigned short* __restrict__ qk, const float* __restrict__ qw,
               const float* __restrict__ kw) {
  const int row = blockIdx.x;
  const int tid = threadIdx.x;
  unsigned short* base = qk + (size_t)row * 2048;
  uint2 uq = *(const uint2*)(base + tid * 4);
  uint2 uk = *(const uint2*)(base + 1024 + tid * 4);
  float q0 = bflo(uq.x), q1 = bfhi(uq.x), q2 = bflo(uq.y), q3 = bfhi(uq.y);
  float k0 = bflo(uk.x), k1 = bfhi(uk.x), k2 = bflo(uk.y), k3 = bfhi(uk.y);
  float sq = q0 * q0 + q1 * q1 + q2 * q2 + q3 * q3;
  float sk = k0 * k0 + k1 * k1 + k2 * k2 + k3 * k3;
#pragma unroll
  for (int off = 32; off > 0; off >>= 1) {
    sq += __shfl_xor(sq, off);
    sk += __shfl_xor(sk, off);
  }
  __shared__ float red[8];
  const int w = tid >> 6;
  if ((tid & 63) == 0) { red[w] = sq; red[4 + w] = sk; }
  __syncthreads();
  sq = red[0] + red[1] + red[2] + red[3];
  sk = red[4] + red[5] + red[6] + red[7];
  const float rq = rsqrtf(sq * (1.0f / 1024.0f) + 1e-6f);
  const float rk = rsqrtf(sk * (1.0f / 1024.0f) + 1e-6f);
  const int c = tid * 4;
  uint2 oq, ok;
  oq.x = (unsigned)f2bf(q0 * rq * qw[c]) | ((unsigned)f2bf(q1 * rq * qw[c + 1]) << 16);
  oq.y = (unsigned)f2bf(q2 * rq * qw[c + 2]) | ((unsigned)f2bf(q3 * rq * qw[c + 3]) << 16);
  ok.x = (unsigned)f2bf(k0 * rk * kw[c]) | ((unsigned)f2bf(k1 * rk * kw[c + 1]) << 16);
  ok.y = (unsigned)f2bf(k2 * rk * kw[c + 2]) | ((unsigned)f2bf(k3 * rk * kw[c + 3]) << 16);
  *(uint2*)(base + tid * 4) = oq;
  *(uint2*)(base + 1024 + tid * 4) = ok;
}

// ---------- MFMA sliding-window ALiBi attention ----------
// One wave per 16 queries of one (b,h). Key window: 32 keys [t0-16, t0+16).
// Swapped QK^T (A=K, B=Q) -> S^T. All global loads (Q, K, all 8 V-frags)
// issued BEFORE the QK^T MFMAs (T14: latency hides under compute).
// V read from tiled Vt2[bh][t>>3][d][t&7]: per load, each 16-lane group reads
// 256B contiguous (coalesced; old [d][t] layout scattered 16 x 4KB apart).
__global__ __launch_bounds__(256)
void k_attn(const unsigned short* __restrict__ qk,   // [8192][2048] q|k (normalized)
            const unsigned short* __restrict__ vt,   // Vt2 tiled
            unsigned short* __restrict__ outb) {     // [8192][1024] bf16
  __shared__ __align__(16) unsigned char plds_all[4][1280];  // 16 rows x 80B
  const int lane = threadIdx.x & 63;
  const int wv = threadIdx.x >> 6;
  unsigned char* plds = plds_all[wv];
  const int bh = blockIdx.y;                 // 0..31
  const int b = bh >> 3, h = bh & 7;
  const int t0 = blockIdx.x * 64 + wv * 16;
  const int g = lane >> 4, c = lane & 15;
  const int jlo = t0 - 16;

  // ---- issue ALL global loads first ----
  // Q B-fragments: Q[t0+c][kc*32 + g*8 .. +8]
  const unsigned short* qrow = qk + (size_t)(b * TSEQ + t0 + c) * 2048 + h * 128 + g * 8;
  bf16x8_t qf[4];
#pragma unroll
  for (int kc = 0; kc < 4; ++kc) qf[kc] = *(const bf16x8_t*)(qrow + kc * 32);

  // K A-fragments (2 key-tiles); clamp negative rows (masked anyway)
  const int j0 = jlo + c;
  const int j0c = (j0 < 0) ? 0 : j0;
  const unsigned short* krow0 = qk + (size_t)(b * TSEQ + j0c) * 2048 + 1024 + h * 128 + g * 8;
  const unsigned short* krow1 = qk + (size_t)(b * TSEQ + t0 + c) * 2048 + 1024 + h * 128 + g * 8;
  bf16x8_t kf0[4], kf1[4];
#pragma unroll
  for (int kc = 0; kc < 4; ++kc) {
    kf0[kc] = *(const bf16x8_t*)(krow0 + kc * 32);
    kf1[kc] = *(const bf16x8_t*)(krow1 + kc * 32);
  }

  // V B-fragments: vf[n][i] = V[jlo + g*8 + i][n*16 + c] = Vt2[bh][tc][n*16+c][i]
  int tc = (jlo >> 3) + g;          // jlo multiple of 16; arithmetic shift ok
  if (tc < 0) tc = 0;               // masked rows: zero P weight
  const unsigned short* vbase = vt + (((size_t)bh * 256 + tc) * 128 + c) * 8;
  bf16x8_t vf[8];
#pragma unroll
  for (int n = 0; n < 8; ++n) vf[n] = *(const bf16x8_t*)(vbase + n * 128);

  // ---- QK^T ----
  f32x4_t s0 = (f32x4_t){0.f, 0.f, 0.f, 0.f};
  f32x4_t s1 = (f32x4_t){0.f, 0.f, 0.f, 0.f};
#pragma unroll
  for (int kc = 0; kc < 4; ++kc) {
    s0 = __builtin_amdgcn_mfma_f32_16x16x32_bf16(kf0[kc], qf[kc], s0, 0, 0, 0);
    s1 = __builtin_amdgcn_mfma_f32_16x16x32_bf16(kf1[kc], qf[kc], s1, 0, 0, 0);
  }

  // scores + mask + bias. key kk = z*16 + g*4 + r; query = c; rel = kk-16-c.
  const float scale = 0.08838834764831845f;  // 1/sqrt(128)
  const float slope = 1.0f / (float)(1 << h);
  float val[8];
#pragma unroll
  for (int z = 0; z < 2; ++z)
#pragma unroll
    for (int r = 0; r < 4; ++r) {
      const int kk = z * 16 + g * 4 + r;
      const int rel = kk - 16 - c;
      const bool ok = (rel <= 0) & (rel >= -WIN) & (jlo + kk >= 0);
      const float sc = (z == 0) ? s0[r] : s1[r];
      val[z * 4 + r] = ok ? (sc * scale + slope * (float)rel) : -1.0e30f;
    }
  float m = val[0];
#pragma unroll
  for (int i = 1; i < 8; ++i) m = fmaxf(m, val[i]);
  m = fmaxf(m, __shfl_xor(m, 16));
  m = fmaxf(m, __shfl_xor(m, 32));
  float e[8], s = 0.f;
#pragma unroll
  for (int i = 0; i < 8; ++i) { e[i] = __expf(val[i] - m); s += e[i]; }
  s += __shfl_xor(s, 16);
  s += __shfl_xor(s, 32);
  const float inv = 1.0f / s;

  // P -> LDS [query c][key kk], row stride 40 elems (80B): 2-way banks = free
#pragma unroll
  for (int z = 0; z < 2; ++z) {
    uint2 pk;
    pk.x = (unsigned)f2bf(e[z * 4 + 0] * inv) | ((unsigned)f2bf(e[z * 4 + 1] * inv) << 16);
    pk.y = (unsigned)f2bf(e[z * 4 + 2] * inv) | ((unsigned)f2bf(e[z * 4 + 3] * inv) << 16);
    *(uint2*)(plds + c * 80 + z * 32 + g * 8) = pk;
  }
  // A-fragment of P: row=c (query), keys g*8..+8
  const bf16x8_t pf = *(const bf16x8_t*)(plds + c * 80 + g * 16);

  // ---- PV ----
  unsigned short* orow = outb + (size_t)(b * TSEQ + t0) * 1024 + h * 128 + c;
#pragma unroll
  for (int n = 0; n < 8; ++n) {
    f32x4_t o = __builtin_amdgcn_mfma_f32_16x16x32_bf16(pf, vf[n], (f32x4_t){0.f, 0.f, 0.f, 0.f},
                                                        0, 0, 0);
#pragma unroll
    for (int r = 0; r < 4; ++r)
      orow[(size_t)(g * 4 + r) * 1024 + n * 16] = f2bf(o[r]);
  }
}

extern "C" void kernel_launch(void* const* d_in, const int* in_sizes, int n_in,
                              void* d_out, int out_size, void* d_ws, size_t ws_size,
                              hipStream_t stream) {
  const float* x = (const float*)d_in[0];
  const float* wq = (const float*)d_in[1];
  const float* wk = (const float*)d_in[2];
  const float* wv = (const float*)d_in[3];
  const float* wo = (const float*)d_in[4];
  const float* qnw = (const float*)d_in[5];
  const float* knw = (const float*)d_in[6];
  float* out = (float*)d_out;

  const int M = 4 * TSEQ;  // 8192 rows
  // workspace (75.5 MB):
  //   xb  [M][1024] bf16 (16.8 MB)  -- x bf16; later reused as attention output
  //   Wt  [4][1024][1024] bf16 (8.4 MB)
  //   qk  [M][2048] bf16 (33.5 MB)  -- q|k (normalized in place)
  //   Vt2 [32][256][128][8] bf16 (16.8 MB) -- V tiled-transposed per (b,h)
  unsigned short* xb = (unsigned short*)d_ws;
  unsigned short* Wt = xb + (size_t)M * DIMW;
  unsigned short* qkb = Wt + (size_t)4 * DIMW * DIMW;
  unsigned short* Vt = qkb + (size_t)M * 2048;
  if (ws_size < ((size_t)M * DIMW + (size_t)4 * DIMW * DIMW + (size_t)M * 2048 +
                 (size_t)M * 2048) * 2) return;

  k_conv_x<<<(M * DIMW / 4 + 255) / 256, 256, 0, stream>>>(x, xb, M * DIMW / 4);
  k_conv_w<<<dim3(32, 32, 4), dim3(32, 8), 0, stream>>>(wq, wk, wv, wo, Wt);
  k_gemm<0><<<dim3(24, 64), 256, 0, stream>>>(xb, Wt, qkb, Vt, nullptr, M, 3072, 1024);
  k_rmsnorm<<<M, 256, 0, stream>>>(qkb, qnw, knw);
  k_attn<<<dim3(TSEQ / 64, 32), 256, 0, stream>>>(qkb, Vt, xb);  // xb = attn out
  k_gemm<1><<<dim3(8, 64), 256, 0, stream>>>(xb, Wt + (size_t)3 * DIMW * DIMW, nullptr,
                                             nullptr, out, M, 1024, 1024);
}